// Round 1
// baseline (508.268 us; speedup 1.0000x reference)
//
#include <hip/hip_runtime.h>

// Problem constants
#define BATCH 128
#define CH    2
#define NN    256
#define DD    256
#define KTOT  131072          // CH*NN*DD
#define KHALF 128             // NN/2

// GEMM tiling
#define NT     64             // N tile (4 tiles)
#define KSPLIT 128            // K splits
#define KLEN   (KTOT / KSPLIT) // 1024 per block
#define KSTEP  16

// ---------------------------------------------------------------------------
// Split-K GEMM: z[b][j] += sum over k-chunk of x[b,k'] * W[r(k')][j]
// k' iterates x's natural layout (c,n,d); W row r = 2*(n*256+d) + c.
// Grid: (4 N-tiles, 128 K-splits). Block: 256 threads.
// Thread owns 4 consecutive b x 8 consecutive j accumulators.
// ---------------------------------------------------------------------------
__global__ __launch_bounds__(256) void gemm_split(const float* __restrict__ x,
                                                  const float* __restrict__ W,
                                                  float* __restrict__ z) {
    const int j0 = blockIdx.x * NT;
    const int k0 = blockIdx.y * KLEN;
    const int t  = threadIdx.x;

    __shared__ float xs[KSTEP][132];   // [k][b], padded (132) for bank spread
    __shared__ float ws_w[KSTEP][NT];  // [k][j]

    const int bq  = t & 31;            // b-quad id  (32)
    const int jg  = t >> 5;            // j-group id (8)
    const int b0  = bq << 2;           // 4 b per thread
    const int jj0 = jg << 3;           // 8 j per thread

    // staging thread mapping
    const int bb = t & 127;            // x stage: one b-row
    const int kh = t >> 7;             // which 8-k half
    const int wrow = t >> 4;           // W stage: row within chunk (16)
    const int wc4  = t & 15;           // float4 column within NT

    float acc[4][8];
#pragma unroll
    for (int i = 0; i < 4; ++i)
#pragma unroll
        for (int j = 0; j < 8; ++j) acc[i][j] = 0.0f;

    for (int ks = 0; ks < KLEN; ks += KSTEP) {
        const int kbase = k0 + ks;
        const int c   = kbase >> 16;      // channel plane (chunk never crosses)
        const int nd0 = kbase & 65535;    // n*256+d base

        // global reads into regs first
        const float4 f0 = *(const float4*)&x[bb * KTOT + kbase + kh * 8];
        const float4 f1 = *(const float4*)&x[bb * KTOT + kbase + kh * 8 + 4];
        const float4 wv = *(const float4*)&W[(2 * (nd0 + wrow) + c) * NN + j0 + wc4 * 4];

        __syncthreads();   // previous iteration's LDS reads done

        // x transpose-stage: xs[k][b]
        const int kb = kh * 8;
        xs[kb + 0][bb] = f0.x; xs[kb + 1][bb] = f0.y;
        xs[kb + 2][bb] = f0.z; xs[kb + 3][bb] = f0.w;
        xs[kb + 4][bb] = f1.x; xs[kb + 5][bb] = f1.y;
        xs[kb + 6][bb] = f1.z; xs[kb + 7][bb] = f1.w;
        // W stage
        *(float4*)&ws_w[wrow][wc4 * 4] = wv;

        __syncthreads();

#pragma unroll
        for (int k = 0; k < KSTEP; ++k) {
            const float4 xv = *(const float4*)&xs[k][b0];
            const float4 w0 = *(const float4*)&ws_w[k][jj0];
            const float4 w1 = *(const float4*)&ws_w[k][jj0 + 4];
            const float xa[4] = {xv.x, xv.y, xv.z, xv.w};
            const float wa[8] = {w0.x, w0.y, w0.z, w0.w, w1.x, w1.y, w1.z, w1.w};
#pragma unroll
            for (int i = 0; i < 4; ++i)
#pragma unroll
                for (int j = 0; j < 8; ++j) acc[i][j] += xa[i] * wa[j];
        }
    }

    // accumulate partials into z
#pragma unroll
    for (int i = 0; i < 4; ++i)
#pragma unroll
        for (int j = 0; j < 8; ++j)
            atomicAdd(&z[(b0 + i) * NN + j0 + jj0 + j], acc[i][j]);
}

// ---------------------------------------------------------------------------
// Selection: per batch row, rank each z value; top-128 are "kept" (strictly
// above the median midpoint for distinct values). Stable compaction of kept
// indices -> idx_att, dropped -> idx_drp.
// ---------------------------------------------------------------------------
__global__ __launch_bounds__(256) void select_kernel(const float* __restrict__ z,
                                                     int* __restrict__ idx_att,
                                                     int* __restrict__ idx_drp) {
    __shared__ float zv[NN];
    __shared__ int   flags[NN];
    const int b = blockIdx.x;
    const int j = threadIdx.x;
    const float v = z[b * NN + j];
    zv[j] = v;
    __syncthreads();
    int rank = 0;
    for (int i = 0; i < NN; ++i) {
        const float u = zv[i];
        rank += (u < v) || (u == v && i < j);   // index tiebreak: exactly 128 kept
    }
    const int kept = (rank >= KHALF) ? 1 : 0;
    flags[j] = kept;
    __syncthreads();
    int pos = 0;
    for (int i = 0; i < j; ++i) pos += flags[i];
    if (kept) idx_att[b * KHALF + pos]       = j;
    else      idx_drp[b * KHALF + (j - pos)] = j;
}

// ---------------------------------------------------------------------------
// Gather: out[b,c,k,:] = x[b,c,att[k],:] + 1e-4 * x[b,c,drp[k],:]
// One 64-lane wave per output row (256 floats = 64 float4).
// ---------------------------------------------------------------------------
__global__ __launch_bounds__(256) void gather_kernel(const float* __restrict__ x,
                                                     const int* __restrict__ idx_att,
                                                     const int* __restrict__ idx_drp,
                                                     float* __restrict__ out) {
    const int row  = blockIdx.x * 4 + (threadIdx.x >> 6);  // (b*2+c)*128+k
    const int lane = threadIdx.x & 63;
    const int k = row & 127;
    const int c = (row >> 7) & 1;
    const int b = row >> 8;
    const int ia = idx_att[b * KHALF + k];
    const int id = idx_drp[b * KHALF + k];
    const float4* pa = (const float4*)&x[((b * 2 + c) * NN + ia) * DD];
    const float4* pd = (const float4*)&x[((b * 2 + c) * NN + id) * DD];
    float4* po = (float4*)&out[(size_t)row * DD];
    const float4 a = pa[lane];
    const float4 d4 = pd[lane];
    float4 o;
    o.x = a.x + 1e-4f * d4.x;
    o.y = a.y + 1e-4f * d4.y;
    o.z = a.z + 1e-4f * d4.z;
    o.w = a.w + 1e-4f * d4.w;
    po[lane] = o;
}

extern "C" void kernel_launch(void* const* d_in, const int* in_sizes, int n_in,
                              void* d_out, int out_size, void* d_ws, size_t ws_size,
                              hipStream_t stream) {
    const float* x = (const float*)d_in[0];
    const float* W = (const float*)d_in[1];
    float* out = (float*)d_out;

    float* z       = (float*)d_ws;                       // 128*256 fp32 = 128 KB
    int*   idx_att = (int*)((char*)d_ws + BATCH * NN * sizeof(float));
    int*   idx_drp = idx_att + BATCH * KHALF;

    hipMemsetAsync(z, 0, BATCH * NN * sizeof(float), stream);

    gemm_split<<<dim3(NN / NT, KSPLIT), 256, 0, stream>>>(x, W, z);
    select_kernel<<<BATCH, 256, 0, stream>>>(z, idx_att, idx_drp);
    gather_kernel<<<BATCH * CH * KHALF / 4, 256, 0, stream>>>(x, idx_att, idx_drp, out);
}

// Round 2
// 327.172 us; speedup vs baseline: 1.5535x; 1.5535x over previous
//
#include <hip/hip_runtime.h>

// Problem constants
#define BATCH 128
#define CH    2
#define NN    256
#define DD    256
#define KTOT  131072          // CH*NN*DD
#define KHALF 128             // NN/2

// GEMM decomposition
#define KSPLIT 256            // one block per CU
#define KLEN   (KTOT / KSPLIT) // 512 k per block
#define KS     32             // k per stage (one MFMA K)
#define NSTAGE (KLEN / KS)    // 16 stages

typedef short bf16x8 __attribute__((ext_vector_type(8)));
typedef float f32x4  __attribute__((ext_vector_type(4)));

__device__ __forceinline__ unsigned int bf16_rne(float f) {
    unsigned int u = __float_as_uint(f);
    return (u + 0x7FFFu + ((u >> 16) & 1u)) >> 16;
}
__device__ __forceinline__ float bf16f(unsigned int h) {
    return __uint_as_float(h << 16);
}

// ---------------------------------------------------------------------------
// Split-K MFMA GEMM, fp32 emulated via bf16 hi/lo 3-pass (hh + hl + lh).
// z_partial[s][b][j] = sum over block s's K-chunk of x[b,k']*W[r(k')][j],
// k' iterates x natural (c,n,d) order; W row r = 2*nd + c.
// Block: 512 threads (8 waves as 2M x 4N, wave tile 64x64). 1 block/CU.
// ---------------------------------------------------------------------------
template <bool ATOMIC>
__global__ __launch_bounds__(512, 2) void gemm_mfma(const float* __restrict__ x,
                                                    const float* __restrict__ W,
                                                    float* __restrict__ zout) {
    // LDS tiles, bf16, rows padded to 40 elements (80 B) for bank spread
    __shared__ unsigned short Ah[128][40], Al[128][40];
    __shared__ unsigned short Bh[256][40], Bl[256][40];

    const int t  = threadIdx.x;
    const int k0 = blockIdx.x * KLEN;
    const int c  = k0 >> 16;          // channel plane (constant per block)
    const int nd_base = k0 & 65535;

    // ---- staging maps ----
    const int tb = t >> 2;            // A: x row (128 rows)
    const int tk = (t & 3) * 8;       // A: 8-k segment within 32
    const int ti = (t >> 6) * 4;      // B: first of 4 k-rows
    const int tj = (t & 63) * 4;      // B: 4-col segment

    float4 xa0, xa1, wb0, wb1, wb2, wb3;

    auto load_stage = [&](int s) {
        const size_t kk = (size_t)k0 + s * KS;
        xa0 = *(const float4*)&x[(size_t)tb * KTOT + kk + tk];
        xa1 = *(const float4*)&x[(size_t)tb * KTOT + kk + tk + 4];
        const int nd0 = nd_base + s * KS + ti;
        wb0 = *(const float4*)&W[(size_t)(2 * (nd0 + 0) + c) * NN + tj];
        wb1 = *(const float4*)&W[(size_t)(2 * (nd0 + 1) + c) * NN + tj];
        wb2 = *(const float4*)&W[(size_t)(2 * (nd0 + 2) + c) * NN + tj];
        wb3 = *(const float4*)&W[(size_t)(2 * (nd0 + 3) + c) * NN + tj];
    };

    auto write_stage = [&]() {
        // A: 8 consecutive k of row tb -> Ah/Al[tb][tk..tk+7] (16B each)
        float v[8] = {xa0.x, xa0.y, xa0.z, xa0.w, xa1.x, xa1.y, xa1.z, xa1.w};
        unsigned int h[8], l[8];
#pragma unroll
        for (int i = 0; i < 8; ++i) {
            h[i] = bf16_rne(v[i]);
            l[i] = bf16_rne(v[i] - bf16f(h[i]));
        }
        uint4 ph, pl;
        ph.x = h[0] | (h[1] << 16); ph.y = h[2] | (h[3] << 16);
        ph.z = h[4] | (h[5] << 16); ph.w = h[6] | (h[7] << 16);
        pl.x = l[0] | (l[1] << 16); pl.y = l[2] | (l[3] << 16);
        pl.z = l[4] | (l[5] << 16); pl.w = l[6] | (l[7] << 16);
        *(uint4*)&Ah[tb][tk] = ph;
        *(uint4*)&Al[tb][tk] = pl;

        // B: 4x4 micro-transpose: rows ti..ti+3 (k), cols tj..tj+3 -> Bh/Bl[col][ti..ti+3]
        const float* r0 = (const float*)&wb0;
        const float* r1 = (const float*)&wb1;
        const float* r2 = (const float*)&wb2;
        const float* r3 = (const float*)&wb3;
#pragma unroll
        for (int cc = 0; cc < 4; ++cc) {
            float w0 = r0[cc], w1 = r1[cc], w2 = r2[cc], w3 = r3[cc];
            unsigned int h0 = bf16_rne(w0), h1 = bf16_rne(w1),
                         h2 = bf16_rne(w2), h3 = bf16_rne(w3);
            unsigned int l0 = bf16_rne(w0 - bf16f(h0)), l1 = bf16_rne(w1 - bf16f(h1)),
                         l2 = bf16_rne(w2 - bf16f(h2)), l3 = bf16_rne(w3 - bf16f(h3));
            uint2 qh, ql;
            qh.x = h0 | (h1 << 16); qh.y = h2 | (h3 << 16);
            ql.x = l0 | (l1 << 16); ql.y = l2 | (l3 << 16);
            *(uint2*)&Bh[tj + cc][ti] = qh;
            *(uint2*)&Bl[tj + cc][ti] = ql;
        }
    };

    // ---- compute maps ----
    const int lane = t & 63;
    const int wv   = t >> 6;
    const int wm   = (wv >> 2) * 64;   // 0 / 64
    const int wn   = (wv & 3) * 64;    // 0 / 64 / 128 / 192
    const int lr   = lane & 15;
    const int kh   = (lane >> 4) * 8;  // 8-k segment of the frag

    f32x4 acc[4][4] = {};

    auto compute_stage = [&]() {
        bf16x8 a_h[4], a_l[4];
#pragma unroll
        for (int mt = 0; mt < 4; ++mt) {
            a_h[mt] = *(const bf16x8*)&Ah[wm + mt * 16 + lr][kh];
            a_l[mt] = *(const bf16x8*)&Al[wm + mt * 16 + lr][kh];
        }
#pragma unroll
        for (int nt = 0; nt < 4; ++nt) {
            bf16x8 b_h = *(const bf16x8*)&Bh[wn + nt * 16 + lr][kh];
            bf16x8 b_l = *(const bf16x8*)&Bl[wn + nt * 16 + lr][kh];
#pragma unroll
            for (int mt = 0; mt < 4; ++mt) {
                acc[mt][nt] = __builtin_amdgcn_mfma_f32_16x16x32_bf16(a_h[mt], b_h, acc[mt][nt], 0, 0, 0);
                acc[mt][nt] = __builtin_amdgcn_mfma_f32_16x16x32_bf16(a_h[mt], b_l, acc[mt][nt], 0, 0, 0);
                acc[mt][nt] = __builtin_amdgcn_mfma_f32_16x16x32_bf16(a_l[mt], b_h, acc[mt][nt], 0, 0, 0);
            }
        }
    };

    load_stage(0);
    for (int s = 0; s < NSTAGE; ++s) {
        __syncthreads();            // previous compute done, LDS reusable
        write_stage();
        __syncthreads();            // stage visible
        if (s + 1 < NSTAGE) load_stage(s + 1);  // fly during compute
        compute_stage();
    }

    // epilogue: C layout col=lane&15, row=(lane>>4)*4+reg  [m89-verified]
#pragma unroll
    for (int mt = 0; mt < 4; ++mt)
#pragma unroll
        for (int nt = 0; nt < 4; ++nt)
#pragma unroll
            for (int r = 0; r < 4; ++r) {
                const int row = wm + mt * 16 + (lane >> 4) * 4 + r;
                const int col = wn + nt * 16 + lr;
                if (ATOMIC) atomicAdd(&zout[row * NN + col], acc[mt][nt][r]);
                else zout[(size_t)blockIdx.x * (BATCH * NN) + row * NN + col] = acc[mt][nt][r];
            }
}

// ---------------------------------------------------------------------------
// Fused split-reduction + median selection. Block = one batch row.
// ---------------------------------------------------------------------------
__global__ __launch_bounds__(256) void reduce_select(const float* __restrict__ part, int nsplit,
                                                     int* __restrict__ idx_att,
                                                     int* __restrict__ idx_drp) {
    __shared__ float zv[NN];
    __shared__ int   flags[NN];
    const int b = blockIdx.x;
    const int j = threadIdx.x;
    float v = 0.0f;
    for (int s = 0; s < nsplit; ++s)
        v += part[(size_t)s * (BATCH * NN) + b * NN + j];
    zv[j] = v;
    __syncthreads();
    int rank = 0;
    for (int i = 0; i < NN; ++i) {
        const float u = zv[i];
        rank += (u < v) || (u == v && i < j);
    }
    const int kept = (rank >= KHALF) ? 1 : 0;
    flags[j] = kept;
    __syncthreads();
    int pos = 0;
    for (int i = 0; i < j; ++i) pos += flags[i];
    if (kept) idx_att[b * KHALF + pos]       = j;
    else      idx_drp[b * KHALF + (j - pos)] = j;
}

// ---------------------------------------------------------------------------
// Gather: out[b,c,k,:] = x[b,c,att[k],:] + 1e-4 * x[b,c,drp[k],:]
// ---------------------------------------------------------------------------
__global__ __launch_bounds__(256) void gather_kernel(const float* __restrict__ x,
                                                     const int* __restrict__ idx_att,
                                                     const int* __restrict__ idx_drp,
                                                     float* __restrict__ out) {
    const int row  = blockIdx.x * 4 + (threadIdx.x >> 6);  // (b*2+c)*128+k
    const int lane = threadIdx.x & 63;
    const int k = row & 127;
    const int c = (row >> 7) & 1;
    const int b = row >> 8;
    const int ia = idx_att[b * KHALF + k];
    const int id = idx_drp[b * KHALF + k];
    const float4* pa = (const float4*)&x[((b * 2 + c) * NN + ia) * DD];
    const float4* pd = (const float4*)&x[((b * 2 + c) * NN + id) * DD];
    float4* po = (float4*)&out[(size_t)row * DD];
    const float4 a  = pa[lane];
    const float4 d4 = pd[lane];
    float4 o;
    o.x = a.x + 1e-4f * d4.x;
    o.y = a.y + 1e-4f * d4.y;
    o.z = a.z + 1e-4f * d4.z;
    o.w = a.w + 1e-4f * d4.w;
    po[lane] = o;
}

extern "C" void kernel_launch(void* const* d_in, const int* in_sizes, int n_in,
                              void* d_out, int out_size, void* d_ws, size_t ws_size,
                              hipStream_t stream) {
    const float* x = (const float*)d_in[0];
    const float* W = (const float*)d_in[1];
    float* out = (float*)d_out;

    const size_t partial_bytes = (size_t)KSPLIT * BATCH * NN * sizeof(float); // 32 MiB
    const size_t idx_bytes = (size_t)BATCH * KHALF * sizeof(int);             // 64 KiB each

    if (ws_size >= partial_bytes + 2 * idx_bytes) {
        // deterministic path: partials in ws, no atomics
        float* part    = (float*)d_ws;
        int*   idx_att = (int*)((char*)d_ws + partial_bytes);
        int*   idx_drp = idx_att + BATCH * KHALF;
        gemm_mfma<false><<<KSPLIT, 512, 0, stream>>>(x, W, part);
        reduce_select<<<BATCH, 256, 0, stream>>>(part, KSPLIT, idx_att, idx_drp);
        gather_kernel<<<BATCH * CH * KHALF / 4, 256, 0, stream>>>(x, idx_att, idx_drp, out);
    } else {
        // fallback: atomic accumulation into z
        float* z       = (float*)d_ws;
        int*   idx_att = (int*)((char*)d_ws + (size_t)BATCH * NN * sizeof(float));
        int*   idx_drp = idx_att + BATCH * KHALF;
        hipMemsetAsync(z, 0, BATCH * NN * sizeof(float), stream);
        gemm_mfma<true><<<KSPLIT, 512, 0, stream>>>(x, W, z);
        reduce_select<<<BATCH, 256, 0, stream>>>(z, 1, idx_att, idx_drp);
        gather_kernel<<<BATCH * CH * KHALF / 4, 256, 0, stream>>>(x, idx_att, idx_drp, out);
    }
}

// Round 3
// 274.646 us; speedup vs baseline: 1.8506x; 1.1912x over previous
//
#include <hip/hip_runtime.h>

// Problem constants
#define BATCH 128
#define CH    2
#define NN    256
#define DD    256
#define KTOT  131072          // CH*NN*DD
#define KHALF 128             // NN/2

// GEMM decomposition
#define KSPLIT 256
#define KLEN   (KTOT / KSPLIT)  // 512 k per K-slice
#define KS     32               // k per stage (one MFMA K)
#define NSTAGE (KLEN / KS)      // 16 stages
#define NTB    128              // cols per block (N half)
#define PITCH  40               // shorts per LDS row (80 B: 16B-aligned, bank-stride 20 -> uniform)

typedef short bf16x8 __attribute__((ext_vector_type(8)));
typedef float f32x4  __attribute__((ext_vector_type(4)));

__device__ __forceinline__ unsigned short bf16_rne(float f) {
    unsigned int u = __float_as_uint(f);
    u += 0x7FFFu + ((u >> 16) & 1u);
    return (unsigned short)(u >> 16);
}
__device__ __forceinline__ float bf16f(unsigned short h) {
    return __uint_as_float(((unsigned int)h) << 16);
}
__device__ __forceinline__ uint4 pack8(const unsigned short* p) {
    uint4 r;
    r.x = (unsigned)p[0] | ((unsigned)p[1] << 16);
    r.y = (unsigned)p[2] | ((unsigned)p[3] << 16);
    r.z = (unsigned)p[4] | ((unsigned)p[5] << 16);
    r.w = (unsigned)p[6] | ((unsigned)p[7] << 16);
    return r;
}

// ---------------------------------------------------------------------------
// Split-K MFMA GEMM, fp32 emulated via bf16 hi/lo 3-pass (hh + hl + lh).
// Block = 256 threads (4 waves as 2M x 2N, wave tile 64x64), tile M=128 N=128.
// Grid = 512: (s, nh) decoded so the nh-pair sharing an x-slice is on one XCD.
// ---------------------------------------------------------------------------
template <bool ATOMIC>
__global__ __launch_bounds__(256, 2) void gemm_mfma(const float* __restrict__ x,
                                                    const float* __restrict__ W,
                                                    float* __restrict__ zout) {
    __shared__ unsigned short Ah[128][PITCH], Al[128][PITCH];
    __shared__ unsigned short Bh[NTB][PITCH], Bl[NTB][PITCH];

    const int bid = blockIdx.x;
    const int s   = ((bid >> 4) << 3) | (bid & 7);  // K-slice 0..255
    const int nh  = (bid >> 3) & 1;                 // N half

    const int t  = threadIdx.x;
    const int k0 = s * KLEN;
    const int c  = k0 >> 16;           // channel plane (slice never crosses)
    const int nd_base = k0 & 65535;

    // staging maps: thread owns one A row-halfk and one B col-halfk
    const int ra = t & 127;            // A: batch row
    const int ha = t >> 7;             // A: k-half (16 floats)
    const int cb = t & 127;            // B: local col
    const int hb = t >> 7;             // B: k-half

    float av[16], bv[16];

    auto load_stage = [&](int st) {
        const float* xp = &x[(size_t)ra * KTOT + k0 + st * KS + 16 * ha];
        *(float4*)&av[0]  = *(const float4*)&xp[0];
        *(float4*)&av[4]  = *(const float4*)&xp[4];
        *(float4*)&av[8]  = *(const float4*)&xp[8];
        *(float4*)&av[12] = *(const float4*)&xp[12];
        const int nd0 = nd_base + st * KS + 16 * hb;
        const float* wp = &W[(size_t)(2 * nd0 + c) * NN + nh * NTB + cb];
#pragma unroll
        for (int i = 0; i < 16; ++i)
            bv[i] = wp[(size_t)i * 2 * NN];   // W row stride 2*NN (interleaved channels)
    };

    auto write_stage = [&]() {
        unsigned short h[16], l[16];
#pragma unroll
        for (int i = 0; i < 16; ++i) {
            h[i] = bf16_rne(av[i]);
            l[i] = bf16_rne(av[i] - bf16f(h[i]));
        }
        *(uint4*)&Ah[ra][16 * ha]     = pack8(h);
        *(uint4*)&Ah[ra][16 * ha + 8] = pack8(h + 8);
        *(uint4*)&Al[ra][16 * ha]     = pack8(l);
        *(uint4*)&Al[ra][16 * ha + 8] = pack8(l + 8);
#pragma unroll
        for (int i = 0; i < 16; ++i) {
            h[i] = bf16_rne(bv[i]);
            l[i] = bf16_rne(bv[i] - bf16f(h[i]));
        }
        *(uint4*)&Bh[cb][16 * hb]     = pack8(h);
        *(uint4*)&Bh[cb][16 * hb + 8] = pack8(h + 8);
        *(uint4*)&Bl[cb][16 * hb]     = pack8(l);
        *(uint4*)&Bl[cb][16 * hb + 8] = pack8(l + 8);
    };

    // compute maps
    const int lane = t & 63;
    const int wid  = t >> 6;
    const int wm   = (wid >> 1) * 64;
    const int wn   = (wid & 1) * 64;
    const int lr   = lane & 15;
    const int kq   = (lane >> 4) * 8;  // 8-k segment of the frag

    f32x4 acc[4][4] = {};

    auto compute_stage = [&]() {
        bf16x8 a_h[4], a_l[4];
#pragma unroll
        for (int mt = 0; mt < 4; ++mt) {
            a_h[mt] = *(const bf16x8*)&Ah[wm + mt * 16 + lr][kq];
            a_l[mt] = *(const bf16x8*)&Al[wm + mt * 16 + lr][kq];
        }
#pragma unroll
        for (int nt = 0; nt < 4; ++nt) {
            bf16x8 b_h = *(const bf16x8*)&Bh[wn + nt * 16 + lr][kq];
            bf16x8 b_l = *(const bf16x8*)&Bl[wn + nt * 16 + lr][kq];
#pragma unroll
            for (int mt = 0; mt < 4; ++mt) {
                acc[mt][nt] = __builtin_amdgcn_mfma_f32_16x16x32_bf16(a_h[mt], b_h, acc[mt][nt], 0, 0, 0);
                acc[mt][nt] = __builtin_amdgcn_mfma_f32_16x16x32_bf16(a_h[mt], b_l, acc[mt][nt], 0, 0, 0);
                acc[mt][nt] = __builtin_amdgcn_mfma_f32_16x16x32_bf16(a_l[mt], b_h, acc[mt][nt], 0, 0, 0);
            }
        }
    };

    load_stage(0);
    for (int st = 0; st < NSTAGE; ++st) {
        __syncthreads();            // previous compute done, LDS reusable
        write_stage();
        __syncthreads();            // stage visible
        if (st + 1 < NSTAGE) load_stage(st + 1);  // in flight during compute
        compute_stage();
    }

    // epilogue: C layout col=lane&15, row=(lane>>4)*4+reg  [verified round 2]
#pragma unroll
    for (int mt = 0; mt < 4; ++mt)
#pragma unroll
        for (int nt = 0; nt < 4; ++nt)
#pragma unroll
            for (int r = 0; r < 4; ++r) {
                const int row = wm + mt * 16 + (lane >> 4) * 4 + r;
                const int col = nh * NTB + wn + nt * 16 + lr;
                if (ATOMIC) atomicAdd(&zout[row * NN + col], acc[mt][nt][r]);
                else zout[(size_t)s * (BATCH * NN) + row * NN + col] = acc[mt][nt][r];
            }
}

// ---------------------------------------------------------------------------
// Stage-1 reduction: 256 K-slices -> 8 groups. Grid 1024 = 8 groups x 128 b.
// ---------------------------------------------------------------------------
__global__ __launch_bounds__(256) void reduce1(const float* __restrict__ part,
                                               float* __restrict__ part2) {
    const int g = blockIdx.x & 7;
    const int b = blockIdx.x >> 3;
    const int j = threadIdx.x;
    float v = 0.0f;
#pragma unroll
    for (int i = 0; i < 32; ++i)
        v += part[(size_t)(g * 32 + i) * (BATCH * NN) + b * NN + j];
    part2[(size_t)g * (BATCH * NN) + b * NN + j] = v;
}

// ---------------------------------------------------------------------------
// Final sum + median selection + stable compaction.
// ---------------------------------------------------------------------------
__global__ __launch_bounds__(256) void select_kernel(const float* __restrict__ p2, int ngroups,
                                                     int* __restrict__ idx_att,
                                                     int* __restrict__ idx_drp) {
    __shared__ float zv[NN];
    __shared__ int   flags[NN];
    const int b = blockIdx.x;
    const int j = threadIdx.x;
    float v = 0.0f;
    for (int g = 0; g < ngroups; ++g)
        v += p2[(size_t)g * (BATCH * NN) + b * NN + j];
    zv[j] = v;
    __syncthreads();
    int rank = 0;
    for (int i = 0; i < NN; ++i) {
        const float u = zv[i];
        rank += (u < v) || (u == v && i < j);
    }
    const int kept = (rank >= KHALF) ? 1 : 0;
    flags[j] = kept;
    __syncthreads();
    int pos = 0;
    for (int i = 0; i < j; ++i) pos += flags[i];
    if (kept) idx_att[b * KHALF + pos]       = j;
    else      idx_drp[b * KHALF + (j - pos)] = j;
}

// ---------------------------------------------------------------------------
// Gather: out[b,c,k,:] = x[b,c,att[k],:] + 1e-4 * x[b,c,drp[k],:]
// ---------------------------------------------------------------------------
__global__ __launch_bounds__(256) void gather_kernel(const float* __restrict__ x,
                                                     const int* __restrict__ idx_att,
                                                     const int* __restrict__ idx_drp,
                                                     float* __restrict__ out) {
    const int row  = blockIdx.x * 4 + (threadIdx.x >> 6);  // (b*2+c)*128+k
    const int lane = threadIdx.x & 63;
    const int k = row & 127;
    const int c = (row >> 7) & 1;
    const int b = row >> 8;
    const int ia = idx_att[b * KHALF + k];
    const int id = idx_drp[b * KHALF + k];
    const float4* pa = (const float4*)&x[((b * 2 + c) * NN + ia) * DD];
    const float4* pd = (const float4*)&x[((b * 2 + c) * NN + id) * DD];
    float4* po = (float4*)&out[(size_t)row * DD];
    const float4 a  = pa[lane];
    const float4 d4 = pd[lane];
    float4 o;
    o.x = a.x + 1e-4f * d4.x;
    o.y = a.y + 1e-4f * d4.y;
    o.z = a.z + 1e-4f * d4.z;
    o.w = a.w + 1e-4f * d4.w;
    po[lane] = o;
}

extern "C" void kernel_launch(void* const* d_in, const int* in_sizes, int n_in,
                              void* d_out, int out_size, void* d_ws, size_t ws_size,
                              hipStream_t stream) {
    const float* x = (const float*)d_in[0];
    const float* W = (const float*)d_in[1];
    float* out = (float*)d_out;

    const size_t part_bytes  = (size_t)KSPLIT * BATCH * NN * sizeof(float);  // 32 MiB
    const size_t part2_bytes = (size_t)8 * BATCH * NN * sizeof(float);       // 1 MiB
    const size_t idx_bytes   = (size_t)BATCH * KHALF * sizeof(int);          // 64 KiB each

    if (ws_size >= part_bytes + part2_bytes + 2 * idx_bytes) {
        // deterministic path: per-slice partials, two-stage reduction
        float* part    = (float*)d_ws;
        float* part2   = (float*)((char*)d_ws + part_bytes);
        int*   idx_att = (int*)((char*)d_ws + part_bytes + part2_bytes);
        int*   idx_drp = idx_att + BATCH * KHALF;
        gemm_mfma<false><<<512, 256, 0, stream>>>(x, W, part);
        reduce1<<<1024, 256, 0, stream>>>(part, part2);
        select_kernel<<<BATCH, 256, 0, stream>>>(part2, 8, idx_att, idx_drp);
        gather_kernel<<<BATCH * CH * KHALF / 4, 256, 0, stream>>>(x, idx_att, idx_drp, out);
    } else {
        // fallback: atomic accumulation into z
        float* z       = (float*)d_ws;
        int*   idx_att = (int*)((char*)d_ws + (size_t)BATCH * NN * sizeof(float));
        int*   idx_drp = idx_att + BATCH * KHALF;
        hipMemsetAsync(z, 0, (size_t)BATCH * NN * sizeof(float), stream);
        gemm_mfma<true><<<512, 256, 0, stream>>>(x, W, z);
        select_kernel<<<BATCH, 256, 0, stream>>>(z, 1, idx_att, idx_drp);
        gather_kernel<<<BATCH * CH * KHALF / 4, 256, 0, stream>>>(x, idx_att, idx_drp, out);
    }
}